// Round 15
// baseline (315.771 us; speedup 1.0000x reference)
//
#include <hip/hip_runtime.h>
#include <hip/hip_cooperative_groups.h>

namespace cg = cooperative_groups;

#define NB   4
#define C_IN 256
#define CQD  64
#define NPT  4096
#define L2E  1.44269504088896f

typedef __attribute__((ext_vector_type(8))) short bf16x8;
typedef __attribute__((ext_vector_type(4))) float f32x4;
typedef unsigned short u16;
typedef unsigned int   u32;

#define EXP2F(x)      __builtin_amdgcn_exp2f(x)
#define MFMA32(A,B,C) __builtin_amdgcn_mfma_f32_16x16x32_bf16(A,B,C,0,0,0)

__device__ __forceinline__ u16 f2bf(float f) {          // RNE (cold paths)
    u32 u = __float_as_uint(f);
    u += 0x7fff + ((u >> 16) & 1);
    return (u16)(u >> 16);
}
// one v_perm: (bf16_trunc(hi)<<16) | bf16_trunc(lo)
__device__ __forceinline__ u32 pack_trunc(float lo, float hi) {
    return __builtin_amdgcn_perm(__float_as_uint(hi), __float_as_uint(lo), 0x07060302u);
}

// ---------------------------------------------------------------------------
// Fragment-major layouts (1 request per wave fragment load):
//   qF/kF: [b][g][half][lane][8] u16, g = seq/16, half = o-chunk/4.
//   vF:    [b][cg][pg][lane][8] u16, cg = c/16, pg = pos/32.
//   wbf:   [go*8+kk][lane][8] u16, stride 512/frag.
// ---------------------------------------------------------------------------

union ProjShared {
    u16 x_t[32][264];                            // [n][c] bf16, stride 528B
    struct { u16 qk[32][136]; u16 vl[256][40]; } ep;
};

union FusedShared {
    ProjShared proj[2];                          // 58368 B
    struct { uint2 p_l[2][2176]; float zl[8][68]; } at;   // 36992 B
};

// ---------------------------------------------------------------------------
// fused: ONE cooperative kernel, grid 256 x 512 (1 block/CU, co-resident).
// Phase 0 prep -> grid.sync -> Phase 1 proj (2 virtual 256-thr tiles/block)
// -> grid.sync -> Phase 2 attn (R11 body verbatim, 56us measured).
// Eliminates all kernel-boundary/launch gaps; fused dispatch duration
// finally measures prep+proj+attn+syncs directly.
// ---------------------------------------------------------------------------
__global__ __launch_bounds__(512, 1) void fused_kernel(
    const float* x, const float* wq, const float* bq,
    const float* wk, const float* bk, const float* wv, const float* bv,
    const float* gamma, u16* wbf, float* bias,
    u16* qF, u16* kF, u16* vF, float* out)
{
    __shared__ FusedShared fsh;
    const int t = threadIdx.x;
    cg::grid_group grid = cg::this_grid();

    // ================= phase 0: prep =================
    {
        const int gid = blockIdx.x*512 + t;      // 256*512 = 131072 >= 98688
        if (gid < 384*256) {
            const int r = gid >> 8, c = gid & 255;
            const float v = (r < 64) ? wq[r*256 + c]
                          : (r < 128) ? wk[(r-64)*256 + c]
                                      : wv[(r-128)*256 + c];
            const int go  = r >> 4, c16 = r & 15;
            const int kk  = c >> 5, qh  = (c >> 3) & 3, j = c & 7;
            wbf[((size_t)(go*8 + kk))*512 + (16*qh + c16)*8 + j] = f2bf(v);
        } else if (gid < 384*256 + 384) {
            const int r = gid - 384*256;
            bias[r] = (r < 64) ? bq[r] : (r < 128) ? bk[r-64] : bv[r-128];
        }
    }
    __threadfence();
    grid.sync();

    // ================= phase 1: proj (2 virtual tiles) =================
    {
        const int grp = t >> 8, tt = t & 255;
        const int vb  = blockIdx.x*2 + grp;      // 0..511
        const int n0  = (vb & 127) * 32;
        const int b   = vb >> 7;
        ProjShared& sh = fsh.proj[grp];

        {   // stage x tile transposed -> bf16 LDS
            const int ln = tt & 31;
            const int cg = tt >> 5;
            #pragma unroll
            for (int rr = 0; rr < 8; rr++) {
                const int c = 4*cg + 32*rr;
                const float f0 = x[((size_t)(b*C_IN + c+0))*NPT + n0 + ln];
                const float f1 = x[((size_t)(b*C_IN + c+1))*NPT + n0 + ln];
                const float f2 = x[((size_t)(b*C_IN + c+2))*NPT + n0 + ln];
                const float f3 = x[((size_t)(b*C_IN + c+3))*NPT + n0 + ln];
                ushort4 u4;
                u4.x = f2bf(f0); u4.y = f2bf(f1); u4.z = f2bf(f2); u4.w = f2bf(f3);
                *(ushort4*)&sh.x_t[ln][c] = u4;
            }
        }
        __syncthreads();

        const int w = tt >> 6, l = tt & 63, q = l >> 4, c16 = l & 15;

        f32x4 acc[6][2];
        #pragma unroll
        for (int ot = 0; ot < 6; ot++)
            #pragma unroll
            for (int nt = 0; nt < 2; nt++)
                acc[ot][nt] = (f32x4){0.f, 0.f, 0.f, 0.f};

        #pragma unroll
        for (int kk = 0; kk < 8; kk++) {
            const bf16x8 bf0 = *(const bf16x8*)&sh.x_t[c16     ][kk*32 + 8*q];
            const bf16x8 bf1 = *(const bf16x8*)&sh.x_t[16 + c16][kk*32 + 8*q];
            #pragma unroll
            for (int ot = 0; ot < 6; ot++) {
                const bf16x8 af = *(const bf16x8*)&wbf[((size_t)((4*ot + w)*8 + kk))*512 + l*8];
                acc[ot][0] = MFMA32(af, bf0, acc[ot][0]);
                acc[ot][1] = MFMA32(af, bf1, acc[ot][1]);
            }
        }
        __syncthreads();   // x_t dead; reuse LDS for epilogue staging

        #pragma unroll
        for (int ot = 0; ot < 6; ot++) {
            const int T  = 4*ot + w;
            const int ob = 16*T + 4*q;
            float b0 = bias[ob+0], b1 = bias[ob+1], b2 = bias[ob+2], b3 = bias[ob+3];
            #pragma unroll
            for (int nt = 0; nt < 2; nt++) {
                const f32x4 a = acc[ot][nt];
                const float v0 = a[0]+b0, v1 = a[1]+b1, v2 = a[2]+b2, v3 = a[3]+b3;
                if (ot < 2) {
                    uint2 u;
                    u.x = (u32)f2bf(v0) | ((u32)f2bf(v1) << 16);
                    u.y = (u32)f2bf(v2) | ((u32)f2bf(v3) << 16);
                    *(uint2*)&sh.ep.qk[16*nt + c16][16*T + 4*q] = u;
                } else {
                    const int cb = 16*T - 128 + 4*q;
                    sh.ep.vl[cb+0][16*nt + c16] = f2bf(v0);
                    sh.ep.vl[cb+1][16*nt + c16] = f2bf(v1);
                    sh.ep.vl[cb+2][16*nt + c16] = f2bf(v2);
                    sh.ep.vl[cb+3][16*nt + c16] = f2bf(v3);
                }
            }
        }
        __syncthreads();

        {   // fragment-major global stores
            const int n    = tt >> 3;
            const int c    = tt & 7;
            const int g    = (n0 + n) >> 4;
            const int lane = 16*(c & 3) + (n & 15);
            const size_t dq = ((size_t)(b*256 + g))*1024 + (size_t)(c >> 2)*512 + lane*8;
            *(uint4*)&qF[dq] = *(uint4*)&sh.ep.qk[n][8*c];
            *(uint4*)&kF[dq] = *(uint4*)&sh.ep.qk[n][64 + 8*c];
            const int cg   = tt >> 4, c16v = tt & 15;
            const int pg   = n0 >> 5;
            u16* vdst = &vF[(((size_t)(b*16 + cg))*128 + pg)*512 + c16v*8];
            #pragma unroll
            for (int j = 0; j < 4; j++)      // lane 16j+c16v -> offset j*128
                *(uint4*)&vdst[j*128] = *(uint4*)&sh.ep.vl[tt][8*j];
        }
    }
    __threadfence();
    grid.sync();

    // ================= phase 2: attn (R11 body, fused softmax) =================
    {
        auto& p_l = fsh.at.p_l;
        auto& zl  = fsh.at.zl;

        const int w = t >> 6, l = t & 63, q = l >> 4, c16 = l & 15;

        const int id  = blockIdx.x;
        const int xcd = id & 7;                    // dispatch round-robins XCDs
        const int jb  = id >> 3;                   // 0..31
        const int b   = xcd >> 1;                  // 2 XCDs per batch -> L2 locality
        const int ntt = ((xcd & 1) << 5) | jb;     // 32 n-tiles per XCD
        const int n0  = ntt * 64;

        // persistent q B-fragments
        bf16x8 qf[4][2];
        #pragma unroll
        for (int nj = 0; nj < 4; nj++) {
            const u16* qp = &qF[((size_t)(b*256 + ntt*4 + nj))*1024 + l*8];
            qf[nj][0] = *(const bf16x8*)qp;
            qf[nj][1] = *(const bf16x8*)(qp + 512);
        }

        f32x4 acc[2][4];
        #pragma unroll
        for (int cg = 0; cg < 2; cg++)
            #pragma unroll
            for (int nj = 0; nj < 4; nj++)
                acc[cg][nj] = (f32x4){0.f, 0.f, 0.f, 0.f};

        float zacc[4] = {0.f, 0.f, 0.f, 0.f};

        const u16* kbase  = &kF[((size_t)(b*256 + w))*1024 + l*8];        // + mt*8192
        const u16* vbase0 = &vF[(((size_t)(b*16 + 2*w))*128)*512 + l*8];  // + (mt*4+kc)*512
        const u16* vbase1 = vbase0 + (size_t)128*512;                     // cg+1

        const int Uw  = (w*16 + q*4)*17 + c16;                    // + nj*17
        const int Ur0 = ((q>>1)*16 + (q&1)*8)*17 + c16;           // + kc*544 + nj*17 (+68)

        // prologue: m-tile 0 scores -> p_l[0]; stage tile-0 v, tile-1 k
        bf16x8 ka0 = *(const bf16x8*)kbase;
        bf16x8 ka1 = *(const bf16x8*)(kbase + 512);
        bf16x8 vac0[4], vac1[4];
        #pragma unroll
        for (int kc = 0; kc < 4; kc++) {
            vac0[kc] = *(const bf16x8*)(vbase0 + (size_t)kc*512);
            vac1[kc] = *(const bf16x8*)(vbase1 + (size_t)kc*512);
        }
        {
            f32x4 s[4];
            #pragma unroll
            for (int nj = 0; nj < 4; nj++) {
                f32x4 a = {0.f, 0.f, 0.f, 0.f};
                a = MFMA32(ka0, qf[nj][0], a);
                a = MFMA32(ka1, qf[nj][1], a);
                s[nj] = a;
            }
            #pragma unroll
            for (int nj = 0; nj < 4; nj++) {
                const float p0 = EXP2F(s[nj][0]*L2E);
                const float p1 = EXP2F(s[nj][1]*L2E);
                const float p2 = EXP2F(s[nj][2]*L2E);
                const float p3 = EXP2F(s[nj][3]*L2E);
                zacc[nj] += (p0 + p1) + (p2 + p3);
                uint2 u;
                u.x = pack_trunc(p0, p1);
                u.y = pack_trunc(p2, p3);
                p_l[0][Uw + nj*17] = u;
            }
        }
        ka0 = *(const bf16x8*)(kbase + 8192);        // m-tile 1
        ka1 = *(const bf16x8*)(kbase + 8192 + 512);

        int buf = 0;
        for (int mt = 0; mt < 31; mt++) {
            __syncthreads();
            // merged region: QK_{mt+1} || PV_mt || exp+z_{mt+1}
            f32x4 s[4];
            #pragma unroll
            for (int nj = 0; nj < 4; nj++) {
                f32x4 a = {0.f, 0.f, 0.f, 0.f};
                a = MFMA32(ka0, qf[nj][0], a);
                a = MFMA32(ka1, qf[nj][1], a);
                s[nj] = a;
            }
            #pragma unroll
            for (int nj = 0; nj < 4; nj++) {
                #pragma unroll
                for (int kc = 0; kc < 4; kc++) {
                    const uint2 u0 = p_l[buf][Ur0 + kc*544 + nj*17];
                    const uint2 u1 = p_l[buf][Ur0 + kc*544 + nj*17 + 68];
                    uint4 f = make_uint4(u0.x, u0.y, u1.x, u1.y);
                    const bf16x8 pf = *(bf16x8*)&f;
                    acc[0][nj] = MFMA32(vac0[kc], pf, acc[0][nj]);
                    acc[1][nj] = MFMA32(vac1[kc], pf, acc[1][nj]);
                }
            }
            // prefetch: k m-tile mt+2 (clamped), v m-tile mt+1
            const int m2 = (mt < 30) ? mt + 2 : 31;
            ka0 = *(const bf16x8*)(kbase + (size_t)m2*8192);
            ka1 = *(const bf16x8*)(kbase + (size_t)m2*8192 + 512);
            bf16x8 van0[4], van1[4];
            #pragma unroll
            for (int kc = 0; kc < 4; kc++) {
                van0[kc] = *(const bf16x8*)(vbase0 + (size_t)((mt+1)*4 + kc)*512);
                van1[kc] = *(const bf16x8*)(vbase1 + (size_t)((mt+1)*4 + kc)*512);
            }

            // exp + z + write p_l[buf^1] for m-tile mt+1
            #pragma unroll
            for (int nj = 0; nj < 4; nj++) {
                const float p0 = EXP2F(s[nj][0]*L2E);
                const float p1 = EXP2F(s[nj][1]*L2E);
                const float p2 = EXP2F(s[nj][2]*L2E);
                const float p3 = EXP2F(s[nj][3]*L2E);
                zacc[nj] += (p0 + p1) + (p2 + p3);
                uint2 u;
                u.x = pack_trunc(p0, p1);
                u.y = pack_trunc(p2, p3);
                p_l[buf^1][Uw + nj*17] = u;
            }
            // rotate prefetch buffers (compile-time indices)
            #pragma unroll
            for (int kc = 0; kc < 4; kc++) {
                vac0[kc] = van0[kc];
                vac1[kc] = van1[kc];
            }
            buf ^= 1;
        }
        // peeled final m-tile (31): PV only
        __syncthreads();
        #pragma unroll
        for (int nj = 0; nj < 4; nj++) {
            #pragma unroll
            for (int kc = 0; kc < 4; kc++) {
                const uint2 u0 = p_l[buf][Ur0 + kc*544 + nj*17];
                const uint2 u1 = p_l[buf][Ur0 + kc*544 + nj*17 + 68];
                uint4 f = make_uint4(u0.x, u0.y, u1.x, u1.y);
                const bf16x8 pf = *(bf16x8*)&f;
                acc[0][nj] = MFMA32(vac0[kc], pf, acc[0][nj]);
                acc[1][nj] = MFMA32(vac1[kc], pf, acc[1][nj]);
            }
        }

        // z: reduce over q (lanes ^16, ^32), then over waves via LDS
        #pragma unroll
        for (int nj = 0; nj < 4; nj++) {
            zacc[nj] += __shfl_xor(zacc[nj], 16, 64);
            zacc[nj] += __shfl_xor(zacc[nj], 32, 64);
        }
        if (q == 0) {
            #pragma unroll
            for (int nj = 0; nj < 4; nj++) zl[w][16*nj + c16] = zacc[nj];
        }
        __syncthreads();

        float rz[4];
        #pragma unroll
        for (int nj = 0; nj < 4; nj++) {
            float zt = 0.f;
            #pragma unroll
            for (int w8 = 0; w8 < 8; w8++) zt += zl[w8][16*nj + c16];
            rz[nj] = 1.0f / zt;
        }

        const float gm = gamma[0];
        #pragma unroll
        for (int cg = 0; cg < 2; cg++)
            #pragma unroll
            for (int nj = 0; nj < 4; nj++)
                #pragma unroll
                for (int r = 0; r < 4; r++) {
                    const size_t o = ((size_t)(b*C_IN + 32*w + 16*cg + 4*q + r))*NPT
                                   + n0 + 16*nj + c16;
                    out[o] = gm*(acc[cg][nj][r]*rz[nj]) + x[o];
                }
    }
}

// ---------------------------------------------------------------------------
extern "C" void kernel_launch(void* const* d_in, const int* in_sizes, int n_in,
                              void* d_out, int out_size, void* d_ws, size_t ws_size,
                              hipStream_t stream)
{
    const float* x     = (const float*)d_in[0];
    const float* wq    = (const float*)d_in[1];
    const float* bq    = (const float*)d_in[2];
    const float* wk    = (const float*)d_in[3];
    const float* bk    = (const float*)d_in[4];
    const float* wv    = (const float*)d_in[5];
    const float* bv    = (const float*)d_in[6];
    const float* gamma = (const float*)d_in[7];
    float* out = (float*)d_out;

    u16* qF  = (u16*)d_ws;                              // 2 MB
    u16* kF  = qF  + (size_t)NB*NPT*CQD;                // 2 MB
    u16* vF  = kF  + (size_t)NB*NPT*CQD;                // 8 MB
    u16* wbf = vF  + (size_t)NB*C_IN*NPT;               // 192 KB
    float* bias = (float*)(wbf + 384*256);              // 384

    void* args[] = {
        (void*)&x, (void*)&wq, (void*)&bq, (void*)&wk, (void*)&bk,
        (void*)&wv, (void*)&bv, (void*)&gamma, (void*)&wbf, (void*)&bias,
        (void*)&qF, (void*)&kF, (void*)&vF, (void*)&out
    };
    hipLaunchCooperativeKernel((const void*)fused_kernel,
                               dim3(256), dim3(512), args, 0, stream);
}